// Round 19
// baseline (16.589 us; speedup 1.0000x reference)
//
#include <hip/hip_runtime.h>
#include <float.h>
#include <math.h>

// Problem constants (from reference)
constexpr int B  = 16;
constexpr int VS = 10475;
constexpr int VO = 8192;
constexpr int K  = 64;
constexpr int PS = 1024;
constexpr int PO = 2048;

// R19: 32x32x16 MFMA hot loop (4x fewer LDS reads than R18's 16x16x32).
// 256 blocks x 1024 thr (16 waves/CU). Block = (k, 256-query chunk).
// Wave = (qgroup of 32 queries) x (object half of 1024): 32 tiles/wave,
// each tile = 1 ds_read_b128 + 1 mfma_f32_32x32x16_f16 + 16 v_min(-d).
// B entry (16B, k0-7) = [ox,oy,oz,w2h, ox,oy,oz,w2l] (fp16); A row =
// [hi(s),-1,lo(s),-1]; dot = s.o_hat - 0.5|o_hat|^2 = -t exactly as R18.
// C/D layout (verified m74/m101): col=lane&31, row=(reg&3)+8*(reg>>2)+4*(lane>>5).
constexpr int BLK   = 1024;
constexpr int QPB   = 256;              // queries per block
constexpr int GRID  = K * (PS / QPB);   // 256
constexpr int NW    = 16;               // waves per block
constexpr int OHALF = PO / 2;           // objects per wave
constexpr int NT    = OHALF / 32;       // 32 tiles per wave

typedef float  v3f    __attribute__((ext_vector_type(3)));
typedef float  f32x16 __attribute__((ext_vector_type(16)));
typedef _Float16 half8 __attribute__((ext_vector_type(8)));
typedef unsigned int u32;
typedef u32 v4u __attribute__((ext_vector_type(4)));

__device__ __forceinline__ u32 pkh(_Float16 lo, _Float16 hi) {
    const unsigned short l = __builtin_bit_cast(unsigned short, lo);
    const unsigned short h = __builtin_bit_cast(unsigned short, hi);
    return ((u32)h << 16) | (u32)l;
}

// ---------------- kernel 1: full min + block partial sum ----------------

__global__ __launch_bounds__(BLK)
void cl_onepass(const float* __restrict__ smplx_v,
                const float* __restrict__ object_v,
                const int*   __restrict__ spi,
                const int*   __restrict__ opi,
                const int*   __restrict__ bidx,
                float*       __restrict__ partial)   // [GRID]
{
    __shared__ u32   so[(PO + 16) * 4];   // 33 KiB object entries + zero pad
    __shared__ float red[NW][32];         //  2 KiB per-wave row minima
    __shared__ float s2lds[QPB];          //  1 KiB |s|^2 per query
    __shared__ float wsum[4];

    const int bk   = blockIdx.x;
    const int tid  = threadIdx.x;
    const int k    = bk >> 2;
    const int ic   = bk & 3;
    const int b    = bidx[k];
    const int wave = tid >> 6;
    const int lane = tid & 63;
    const int qg   = wave & 7;            // query group (32 queries)
    const int oh   = wave >> 3;           // object half (0/1)

    // ---- stage objects: 2/thread, dwordx3, fp16-round + w2 hi/lo split ----
    const float* __restrict__ ov = object_v + (size_t)b * VO * 3;
    #pragma unroll
    for (int r = 0; r < PO / BLK; ++r) {
        const int j  = r * BLK + tid;
        const int oj = opi[k * PO + j];
        const v3f p  = *(const v3f*)(ov + 3 * (size_t)oj);
        const _Float16 hx = (_Float16)p.x, hy = (_Float16)p.y, hz = (_Float16)p.z;
        const float fx = (float)hx, fy = (float)hy, fz = (float)hz;
        const float w2 = 0.5f * (fx * fx + fy * fy + fz * fz);
        const _Float16 w2h = (_Float16)w2;
        const _Float16 w2l = (_Float16)(w2 - (float)w2h);
        const u32 d0 = pkh(hx, hy);
        *(v4u*)&so[j * 4] = (v4u){d0, pkh(hz, w2h), d0, pkh(hz, w2l)};
    }
    if (tid < 64) so[PO * 4 + tid] = 0;   // zero pad (lanes>=32 B-frag)

    // ---- queries: lanes 0-31 of every wave load query qg*32+lane ----
    half8 afrag = (half8)(_Float16)0;
    if (lane < 32) {
        const int i  = ic * QPB + qg * 32 + lane;
        const int si = spi[k * PS + i];
        const v3f s  = *(const v3f*)(smplx_v + 3 * ((size_t)b * VS + si));
        const float s2 = s.x * s.x + s.y * s.y + s.z * s.z;
        const _Float16 shx = (_Float16)s.x, shy = (_Float16)s.y, shz = (_Float16)s.z;
        const _Float16 slx = (_Float16)(s.x - (float)shx);
        const _Float16 sly = (_Float16)(s.y - (float)shy);
        const _Float16 slz = (_Float16)(s.z - (float)shz);
        const _Float16 n1  = (_Float16)(-1.0f);
        afrag = (half8){shx, shy, shz, n1, slx, sly, slz, n1};
        if (wave < 8) s2lds[qg * 32 + lane] = s2;   // single writer per query
    }
    __syncthreads();

    // ---- per-lane B pointer: lanes 0-31 walk this half's entries ----
    const u32* bp  = (lane < 32) ? &so[((size_t)oh * OHALF + (lane & 31)) * 4]
                                 : &so[PO * 4];
    const int  inc = (lane < 32) ? 32 * 4 : 0;   // u32 stride per tile

    // ---- hot loop: 32 tiles, 1 MFMA(32x32x16) + 16 negated v_min each ----
    f32x16 mint;
    #pragma unroll
    for (int i = 0; i < 16; ++i) mint[i] = FLT_MAX;

    #pragma unroll 4
    for (int t = 0; t < NT; ++t) {
        const half8 bfrag = *(const half8*)bp;
        f32x16 zc;
        #pragma unroll
        for (int i = 0; i < 16; ++i) zc[i] = 0.0f;
        const f32x16 d = __builtin_amdgcn_mfma_f32_32x32x16_f16(
            afrag, bfrag, zc, 0, 0, 0);
        #pragma unroll
        for (int i = 0; i < 16; ++i) mint[i] = fminf(mint[i], -d[i]);
        bp += inc;
    }

    // ---- per-row min over the 32 cols (xor within each 32-lane half) ----
    #pragma unroll
    for (int m = 1; m <= 16; m <<= 1) {
        #pragma unroll
        for (int i = 0; i < 16; ++i)
            mint[i] = fminf(mint[i], __shfl_xor(mint[i], m, 64));
    }

    // ---- write row minima (lane 0: rows r%8<4; lane 32: rows r%8>=4) ----
    if ((lane & 31) == 0) {
        const int h = lane >> 5;
        #pragma unroll
        for (int reg = 0; reg < 16; ++reg) {
            const int row = (reg & 3) + 8 * (reg >> 2) + 4 * h;
            red[wave][row] = mint[reg];
        }
    }
    __syncthreads();

    // ---- finalize: thread tid<256 owns query tid; min over 2 halves ----
    float d = 0.0f;
    if (tid < QPB) {
        const int q2 = tid >> 5, row = tid & 31;
        const float m = fminf(red[q2][row], red[q2 + 8][row]);
        d = sqrtf(fmaxf(fmaf(2.0f, m, s2lds[tid]), 0.0f));
    }
    #pragma unroll
    for (int off = 32; off > 0; off >>= 1)
        d += __shfl_down(d, off, 64);
    if (lane == 0 && wave < 4) wsum[wave] = d;
    __syncthreads();
    if (tid == 0) partial[bk] = (wsum[0] + wsum[1]) + (wsum[2] + wsum[3]);
}

// ---------------- kernel 2: final 256 -> 1 reduce (one wave) ----------------

__global__ __launch_bounds__(64)
void cl_final(const float* __restrict__ partial, float* __restrict__ out)
{
    const int t = threadIdx.x;
    const float4 a = ((const float4*)partial)[t];   // 64 lanes x 4 = 256
    float v = (a.x + a.y) + (a.z + a.w);
    #pragma unroll
    for (int off = 32; off > 0; off >>= 1)
        v += __shfl_down(v, off, 64);
    if (t == 0) out[0] = v * (1.0f / (float)(K * PS));
}

// ---------------- launcher ----------------

extern "C" void kernel_launch(void* const* d_in, const int* in_sizes, int n_in,
                              void* d_out, int out_size, void* d_ws, size_t ws_size,
                              hipStream_t stream)
{
    const float* smplx_v       = (const float*)d_in[0];
    const float* object_v      = (const float*)d_in[1];
    const int*   smpl_part_idx = (const int*)d_in[2];
    const int*   obj_part_idx  = (const int*)d_in[3];
    const int*   batch_idx     = (const int*)d_in[4];
    float*       out           = (float*)d_out;

    float* partial = (float*)d_ws;   // GRID floats

    cl_onepass<<<GRID, BLK, 0, stream>>>(
        smplx_v, object_v, smpl_part_idx, obj_part_idx, batch_idx, partial);
    cl_final<<<1, 64, 0, stream>>>(partial, out);
}

// Round 20
// 15.681 us; speedup vs baseline: 1.0579x; 1.0579x over previous
//
#include <hip/hip_runtime.h>
#include <float.h>
#include <math.h>

// Problem constants (from reference)
constexpr int B  = 16;
constexpr int VS = 10475;
constexpr int VO = 8192;
constexpr int K  = 64;
constexpr int PS = 1024;
constexpr int PO = 2048;

// R20: 32x32x16 MFMA with SELF-CONTAINED waves (R19 loop + R18-light epilogue).
// 256 blocks x 512 thr (8 waves/CU). Block = (k, 256-query chunk);
// wave = 32-query group x ALL 2048 objects = 64 tiles:
//   tile = 1 ds_read_b128 + 1 mfma_f32_32x32x16_f16 + 16 v_min(-d).
// B entry (16B, k0-7) = [ox,oy,oz,w2h, ox,oy,oz,w2l] (fp16, verified R18/19);
// A row = [hi(s),-1,lo(s),-1]; lanes>=32 carry zero fragments (k8-15 = 0).
// Epilogue: 5 xor-min rounds -> every lane of half h holds that half's 16
// row-minima (halves partition the 32 rows) -> static 15-op select + 2
// shuffles put row l's min in lane l (where s2 already lives). No LDS
// epilogue, no extra barrier, no cross-wave combine.
// C/D layout (m74/m101): col=lane&31, row=(reg&3)+8*(reg>>2)+4*(lane>>5).
constexpr int BLK  = 512;
constexpr int QPB  = 256;              // queries per block
constexpr int GRID = K * (PS / QPB);   // 256
constexpr int NW   = 8;                // waves per block
constexpr int NT   = PO / 32;          // 64 tiles per wave

typedef float  v3f    __attribute__((ext_vector_type(3)));
typedef float  f32x16 __attribute__((ext_vector_type(16)));
typedef _Float16 half8 __attribute__((ext_vector_type(8)));
typedef unsigned int u32;
typedef u32 v4u __attribute__((ext_vector_type(4)));

__device__ __forceinline__ u32 pkh(_Float16 lo, _Float16 hi) {
    const unsigned short l = __builtin_bit_cast(unsigned short, lo);
    const unsigned short h = __builtin_bit_cast(unsigned short, hi);
    return ((u32)h << 16) | (u32)l;
}

// ---------------- kernel 1: full min + block partial sum ----------------

__global__ __launch_bounds__(BLK)
void cl_onepass(const float* __restrict__ smplx_v,
                const float* __restrict__ object_v,
                const int*   __restrict__ spi,
                const int*   __restrict__ opi,
                const int*   __restrict__ bidx,
                float*       __restrict__ partial)   // [GRID]
{
    __shared__ u32   so[(PO + 16) * 4];   // 33 KiB object entries + zero pad
    __shared__ float wsum[NW];

    const int bk   = blockIdx.x;
    const int tid  = threadIdx.x;
    const int k    = bk >> 2;
    const int ic   = bk & 3;
    const int b    = bidx[k];
    const int wave = tid >> 6;            // qgroup 0..7
    const int lane = tid & 63;

    // ---- stage objects: 4/thread, dwordx3, fp16-round + w2 hi/lo split ----
    const float* __restrict__ ov = object_v + (size_t)b * VO * 3;
    #pragma unroll
    for (int r = 0; r < PO / BLK; ++r) {
        const int j  = r * BLK + tid;
        const int oj = opi[k * PO + j];
        const v3f p  = *(const v3f*)(ov + 3 * (size_t)oj);
        const _Float16 hx = (_Float16)p.x, hy = (_Float16)p.y, hz = (_Float16)p.z;
        const float fx = (float)hx, fy = (float)hy, fz = (float)hz;
        const float w2 = 0.5f * (fx * fx + fy * fy + fz * fz);
        const _Float16 w2h = (_Float16)w2;
        const _Float16 w2l = (_Float16)(w2 - (float)w2h);
        const u32 d0 = pkh(hx, hy);
        *(v4u*)&so[j * 4] = (v4u){d0, pkh(hz, w2h), d0, pkh(hz, w2l)};
    }
    if (tid < 64) so[PO * 4 + tid] = 0;   // zero pad (lanes>=32 B-frag)

    // ---- queries: lanes 0-31 load query wave*32+lane; s2 stays in-lane ----
    half8 afrag = (half8)(_Float16)0;
    float s2 = 0.0f;
    if (lane < 32) {
        const int i  = ic * QPB + wave * 32 + lane;
        const int si = spi[k * PS + i];
        const v3f s  = *(const v3f*)(smplx_v + 3 * ((size_t)b * VS + si));
        s2 = s.x * s.x + s.y * s.y + s.z * s.z;
        const _Float16 shx = (_Float16)s.x, shy = (_Float16)s.y, shz = (_Float16)s.z;
        const _Float16 slx = (_Float16)(s.x - (float)shx);
        const _Float16 sly = (_Float16)(s.y - (float)shy);
        const _Float16 slz = (_Float16)(s.z - (float)shz);
        const _Float16 n1  = (_Float16)(-1.0f);
        afrag = (half8){shx, shy, shz, n1, slx, sly, slz, n1};
    }
    __syncthreads();

    // ---- per-lane B pointer: lanes 0-31 walk all 2048 entries ----
    const u32* bp  = (lane < 32) ? &so[(lane & 31) * 4] : &so[PO * 4];
    const int  inc = (lane < 32) ? 32 * 4 : 0;   // u32 stride per tile

    // ---- hot loop: 64 tiles, 1 MFMA(32x32x16) + 16 negated v_min each ----
    f32x16 mint;
    #pragma unroll
    for (int i = 0; i < 16; ++i) mint[i] = FLT_MAX;

    #pragma unroll 4
    for (int t = 0; t < NT; ++t) {
        const half8 bfrag = *(const half8*)bp;
        f32x16 zc;
        #pragma unroll
        for (int i = 0; i < 16; ++i) zc[i] = 0.0f;
        const f32x16 d = __builtin_amdgcn_mfma_f32_32x32x16_f16(
            afrag, bfrag, zc, 0, 0, 0);
        #pragma unroll
        for (int i = 0; i < 16; ++i) mint[i] = fminf(mint[i], -d[i]);
        bp += inc;
    }

    // ---- per-row min over 32 cols (xor within each 32-lane half) ----
    #pragma unroll
    for (int m = 1; m <= 16; m <<= 1) {
        #pragma unroll
        for (int i = 0; i < 16; ++i)
            mint[i] = fminf(mint[i], __shfl_xor(mint[i], m, 64));
    }

    // ---- route row l's min to lane l (static select + 2 shuffles) ----
    // row = (reg&3) + 8*(reg>>2) + 4*h  =>  reg(l) = (l&3) | ((l>>3)<<2),
    // h(l) = (l>>2)&1. Lane 32+l computes sel for the same reg(l).
    const int mm  = lane & 31;
    const int reg = (mm & 3) | ((mm >> 3) << 2);
    float sel = mint[0];
    #pragma unroll
    for (int r = 1; r < 16; ++r) sel = (reg == r) ? mint[r] : sel;
    const float vA = __shfl(sel, mm, 64);        // half-0 value for reg(mm)
    const float vB = __shfl(sel, mm + 32, 64);   // half-1 value for reg(mm)
    const float d2m = ((mm >> 2) & 1) ? vB : vA;

    float d = 0.0f;
    if (lane < 32)
        d = sqrtf(fmaxf(fmaf(2.0f, d2m, s2), 0.0f));

    // ---- wave sum (lanes 0-31 carry values) ----
    #pragma unroll
    for (int m = 1; m <= 16; m <<= 1)
        d += __shfl_xor(d, m, 64);
    if (lane == 0) wsum[wave] = d;
    __syncthreads();

    if (tid < 64) {
        float v = (tid < NW) ? wsum[tid] : 0.0f;
        #pragma unroll
        for (int off = 4; off > 0; off >>= 1)
            v += __shfl_down(v, off, 64);
        if (tid == 0) partial[bk] = v;
    }
}

// ---------------- kernel 2: final 256 -> 1 reduce (one wave) ----------------

__global__ __launch_bounds__(64)
void cl_final(const float* __restrict__ partial, float* __restrict__ out)
{
    const int t = threadIdx.x;
    const float4 a = ((const float4*)partial)[t];   // 64 lanes x 4 = 256
    float v = (a.x + a.y) + (a.z + a.w);
    #pragma unroll
    for (int off = 32; off > 0; off >>= 1)
        v += __shfl_down(v, off, 64);
    if (t == 0) out[0] = v * (1.0f / (float)(K * PS));
}

// ---------------- launcher ----------------

extern "C" void kernel_launch(void* const* d_in, const int* in_sizes, int n_in,
                              void* d_out, int out_size, void* d_ws, size_t ws_size,
                              hipStream_t stream)
{
    const float* smplx_v       = (const float*)d_in[0];
    const float* object_v      = (const float*)d_in[1];
    const int*   smpl_part_idx = (const int*)d_in[2];
    const int*   obj_part_idx  = (const int*)d_in[3];
    const int*   batch_idx     = (const int*)d_in[4];
    float*       out           = (float*)d_out;

    float* partial = (float*)d_ws;   // GRID floats

    cl_onepass<<<GRID, BLK, 0, stream>>>(
        smplx_v, object_v, smpl_part_idx, obj_part_idx, batch_idx, partial);
    cl_final<<<1, 64, 0, stream>>>(partial, out);
}